// Round 10
// baseline (507.075 us; speedup 1.0000x reference)
//
#include <hip/hip_runtime.h>
#include <hip/hip_bf16.h>
#include <math.h>

// ---------------------------------------------------------------------------
// FederatedPPOAgent: 3x GCNConv (N=100k, E=3.2M, D=128) + actor/critic MLPs.
//
// R10 changes vs R9:
//  - ALL inter-kernel activations fp8 e4m3 (scale S2=32, folded into
//    epilogues): h, h3, A1C1. gemm2 gains AMODE=2 (fp8-A staging, 1/S2
//    folded into epilogue); agg kernels emit fp8 directly (uint2 stores).
//    ~115MB less coalesced stream traffic.
//  - CSR: sum_hist_dinv + chunk_sum fused. 21 -> 19 dispatches.
//  - agg128 left as-is (R7/R8 control: 162MB L2-miss/fabric traffic at
//    2.9 TB/s is the saturated path; inst-count halving was time-neutral).
// ---------------------------------------------------------------------------

#define WS_ALIGN(x) (((x) + 255) & ~(size_t)255)

constexpr int RNG  = 64;        // node ranges
constexpr int NRG  = 1563;      // nodes per range (64*1563 >= 100000)
constexpr int NB   = 1024;      // bucket-phase blocks
constexpr int CHK  = 16;        // per-range fill chunks

constexpr float S_FP8     = 64.0f;   // hprime scale
constexpr float S_FP8_INV = 1.0f / 64.0f;
constexpr float S2        = 32.0f;   // activation (h/h3/A1C1) scale
constexpr float S2I       = 1.0f / 32.0f;

using bf16x8 = __attribute__((ext_vector_type(8))) short;
using f32x4  = __attribute__((ext_vector_type(4))) float;
using f32x2  = __attribute__((ext_vector_type(2))) float;

__device__ __forceinline__ float b2f(unsigned short u) {
    return __uint_as_float(((unsigned int)u) << 16);
}
__device__ __forceinline__ unsigned short f2b(float f) {
    __hip_bfloat16 hb = __float2bfloat16(f);
    return *(unsigned short*)&hb;
}
__device__ __forceinline__ unsigned char f2fp8(float f) {
    return (unsigned char)(__builtin_amdgcn_cvt_pk_fp8_f32(f, f, 0, false) & 0xff);
}
__device__ __forceinline__ int pad8(int v) { return (v + 7) & ~7; }

// 8 fp8 (uint2) -> 4 packed-f32 accumulators
__device__ __forceinline__ void acc8(uint2 u, f32x2& a01, f32x2& a23,
                                     f32x2& a45, f32x2& a67) {
    a01 += __builtin_amdgcn_cvt_pk_f32_fp8((int)u.x, false);
    a23 += __builtin_amdgcn_cvt_pk_f32_fp8((int)u.x, true);
    a45 += __builtin_amdgcn_cvt_pk_f32_fp8((int)u.y, false);
    a67 += __builtin_amdgcn_cvt_pk_f32_fp8((int)u.y, true);
}

// ---------------- CSR build ----------------

__global__ __launch_bounds__(256) void bucket_count_k(
    const int* __restrict__ dst, int* __restrict__ bcnt, int E) {
    __shared__ int c64[RNG];
    int b = blockIdx.x, t = threadIdx.x;
    if (t < RNG) c64[t] = 0;
    __syncthreads();
    int ec = (E + NB - 1) / NB;
    int e0 = b * ec, e1 = min(E, e0 + ec);
    for (int e = e0 + t; e < e1; e += 256) {
        int d = __builtin_nontemporal_load(dst + e);
        atomicAdd(&c64[d / NRG], 1);
    }
    __syncthreads();
    if (t < RNG) bcnt[t * NB + b] = c64[t];
}

__global__ __launch_bounds__(256) void rsum_k(
    const int* __restrict__ bcnt, int* __restrict__ base, int* __restrict__ rtot) {
    __shared__ int s[256];
    int r = blockIdx.x, t = threadIdx.x;
    const int* row = bcnt + (size_t)r * NB;
    int v[4], loc = 0;
#pragma unroll
    for (int j = 0; j < 4; j++) { v[j] = row[t * 4 + j]; loc += v[j]; }
    s[t] = loc;
    __syncthreads();
    for (int d = 1; d < 256; d <<= 1) {
        int x = (t >= d) ? s[t - d] : 0;
        __syncthreads();
        s[t] += x;
        __syncthreads();
    }
    int run = s[t] - loc;   // exclusive
    int* bp = base + (size_t)r * NB + t * 4;
#pragma unroll
    for (int j = 0; j < 4; j++) { bp[j] = run; run += v[j]; }
    if (t == 255) rtot[r] = s[255];
}

__global__ void rstart_k(const int* __restrict__ rtot, int* __restrict__ bstart) {
    if (threadIdx.x == 0) {
        int run = 0;
        for (int r = 0; r < RNG; r++) { bstart[r] = run; run += rtot[r]; }
        bstart[RNG] = run;
    }
}

__global__ __launch_bounds__(256) void bucket_scatter_k(
    const int* __restrict__ src, const int* __restrict__ dst,
    const int* __restrict__ base, const int* __restrict__ bstart,
    unsigned* __restrict__ bucket, int E) {
    __shared__ int cur[RNG];
    int b = blockIdx.x, t = threadIdx.x;
    if (t < RNG) cur[t] = bstart[t] + base[(size_t)t * NB + b];
    __syncthreads();
    int ec = (E + NB - 1) / NB;
    int e0 = b * ec, e1 = min(E, e0 + ec);
    for (int e = e0 + t; e < e1; e += 256) {
        int d = __builtin_nontemporal_load(dst + e);
        int sv = __builtin_nontemporal_load(src + e);
        int r = d / NRG;
        int pos = atomicAdd(&cur[r], 1);
        bucket[pos] = ((unsigned)(d - r * NRG) << 17) | (unsigned)sv;
    }
}

__global__ __launch_bounds__(256) void hist_bucket_k(
    const unsigned* __restrict__ bucket, const int* __restrict__ bstart,
    int* __restrict__ hist) {
    __shared__ int h[NRG];
    int b = blockIdx.x, r = b & 63, c2 = b >> 6, t = threadIdx.x;
    for (int i = t; i < NRG; i += 256) h[i] = 0;
    int s0 = bstart[r], s1 = bstart[r + 1];
    int ec = (s1 - s0 + CHK - 1) / CHK;
    int e0 = s0 + c2 * ec, e1 = min(s1, e0 + ec);
    __syncthreads();
    for (int e = e0 + t; e < e1; e += 256) {
        unsigned v = __builtin_nontemporal_load(bucket + e);
        atomicAdd(&h[v >> 17], 1);
    }
    __syncthreads();
    int* out = hist + ((size_t)r * CHK + c2) * NRG;
    for (int i = t; i < NRG; i += 256) out[i] = h[i];
}

// cnt + dinv + per-block padded sum (fuses old sum_hist_dinv + chunk_sum)
__global__ void sum_hist_dinv_chunk_k(const int* __restrict__ hist,
                                      int* __restrict__ cnt, float* __restrict__ dinv,
                                      int* __restrict__ bsum, int N) {
    __shared__ int sd[256];
    int t = threadIdx.x;
    int i = blockIdx.x * 256 + t;
    int s = 0;
    if (i < N) {
        int r = i / NRG, li = i - r * NRG;
        const int* hp = hist + ((size_t)r * CHK) * NRG + li;
#pragma unroll
        for (int c = 0; c < CHK; c++) s += hp[(size_t)c * NRG];
        cnt[i] = s;
        dinv[i] = rsqrtf((float)s + 1.0f);   // +1: self loop
    }
    sd[t] = (i < N) ? pad8(s) : 0;
    __syncthreads();
    for (int d = 128; d > 0; d >>= 1) {
        if (t < d) sd[t] += sd[t + d];
        __syncthreads();
    }
    if (t == 0) bsum[blockIdx.x] = sd[0];
}

__global__ void scan_mid_k(const int* __restrict__ bsum, int* __restrict__ boff,
                           int nb, int* __restrict__ rowptr, int N) {
    __shared__ int s[512];
    int t = threadIdx.x;
    s[t] = (t < nb) ? bsum[t] : 0;
    __syncthreads();
    if (t == 0) {
        int run = 0;
        for (int i = 0; i < nb; i++) { int v = s[i]; s[i] = run; run += v; }
        rowptr[N] = run;
    }
    __syncthreads();
    if (t < nb) boff[t] = s[t];
}

// scan_final + offsets + pad_col fused
__global__ void scan_off_pad_k(const int* __restrict__ cnt, const int* __restrict__ boff,
                               int* __restrict__ rowptr, int* __restrict__ hist,
                               int* __restrict__ col, int N) {
    __shared__ int s[256];
    int t = threadIdx.x;
    int i = blockIdx.x * 256 + t;
    int cv = (i < N) ? cnt[i] : 0;
    int v = (i < N) ? pad8(cv) : 0;
    s[t] = v;
    __syncthreads();
    for (int d = 1; d < 256; d <<= 1) {
        int x = (t >= d) ? s[t - d] : 0;
        __syncthreads();
        s[t] += x;
        __syncthreads();
    }
    if (i < N) {
        int rp = s[t] - v + boff[blockIdx.x];
        rowptr[i] = rp;
        int r = i / NRG, li = i - r * NRG;
        int* hp = hist + ((size_t)r * CHK) * NRG + li;
        int run = rp;
#pragma unroll
        for (int c = 0; c < CHK; c++) {
            int hv = hp[(size_t)c * NRG];
            hp[(size_t)c * NRG] = run;
            run += hv;
        }
        for (int e = rp + cv; e < rp + v; e++) col[e] = N;
    }
}

__global__ __launch_bounds__(256) void fill2_k(
    const unsigned* __restrict__ bucket, const int* __restrict__ bstart,
    const int* __restrict__ hist, int* __restrict__ col) {
    __shared__ int cur[NRG];
    int b = blockIdx.x, r = b & 63, c2 = b >> 6, t = threadIdx.x;
    const int* hp = hist + ((size_t)r * CHK + c2) * NRG;
    for (int i = t; i < NRG; i += 256) cur[i] = hp[i];
    int s0 = bstart[r], s1 = bstart[r + 1];
    int ec = (s1 - s0 + CHK - 1) / CHK;
    int e0 = s0 + c2 * ec, e1 = min(s1, e0 + ec);
    __syncthreads();
    for (int e = e0 + t; e < e1; e += 256) {
        unsigned v = __builtin_nontemporal_load(bucket + e);
        int slot = atomicAdd(&cur[v >> 17], 1);   // LDS atomic
        col[slot] = (int)(v & 0x1FFFFu);
    }
}

// ---------------- weight prep: fp32 W[K][OUT] -> bf16 W^T[OUT][K] ----------------

__global__ __launch_bounds__(256) void prep_w_k(
    const float* __restrict__ W1, const float* __restrict__ W2,
    const float* __restrict__ W3, const float* __restrict__ Wa1,
    const float* __restrict__ Wc1, const float* __restrict__ Wa2,
    const float* __restrict__ Wc2, unsigned short* __restrict__ wt) {
    int i = blockIdx.x * 256 + threadIdx.x;   // 0..73727
    const float* W; int off, K, OUT;
    if (i < 16384)      { W = W1;  off = 0;     K = 128; OUT = 128; }
    else if (i < 32768) { W = W2;  off = 16384; K = 128; OUT = 128; }
    else if (i < 40960) { W = W3;  off = 32768; K = 128; OUT = 64; }
    else if (i < 49152) { W = Wa1; off = 40960; K = 64;  OUT = 128; }
    else if (i < 57344) { W = Wc1; off = 49152; K = 64;  OUT = 128; }
    else if (i < 65536) { W = Wa2; off = 57344; K = 128; OUT = 64; }
    else                { W = Wc2; off = 65536; K = 128; OUT = 64; }
    int j = i - off, k = j / OUT, n = j - k * OUT;
    wt[off + n * K + k] = f2b(W[j]);
}

// ---------------- gemm2: weights-stationary grid-stride MFMA GEMM ----------------
// AMODE: 0 = fp32 A, 2 = fp8 A (values pre-scaled by S2; S2I folded in epilogue)
// EPI 0: fp8(acc * AIN * dinv[row] * S_FP8), unguarded rows (zero pad-row at N)
// EPI 1: fp8(relu(acc*AIN + concat-bias) * S2)
// EPI 2: actor tail: v=relu(acc*AIN+sb[col]); logits=v@w3+b3; softmax -> out[0..8)
// EPI 3: critic tail: v=relu(acc*AIN+sb[col]); value=v@w3+b3 -> out[8]

template <int K, int OUT, int EPI, int AMODE>
__global__ __launch_bounds__(256) void gemm2_k(
    const void* __restrict__ Xv, int ldx, const unsigned short* __restrict__ Wt,
    const float* __restrict__ sb, const float* __restrict__ w3b,
    const float* __restrict__ b3, void* __restrict__ Yv, int N, int NT) {
    constexpr int LDK = K + 8;
    constexpr float AIN = (AMODE == 2) ? S2I : 1.0f;
    __shared__ __align__(16) unsigned short Bs[OUT * LDK];
    __shared__ __align__(16) unsigned short As[64 * LDK];
    int t = threadIdx.x;

    for (int g = t; g < OUT * (K / 8); g += 256) {
        int r = g / (K / 8), q = g - r * (K / 8);
        *(uint4*)&Bs[r * LDK + q * 8] = *(const uint4*)(Wt + r * K + q * 8);
    }

    int wv = t >> 6, lane = t & 63;
    int lm = lane & 15, lq = lane >> 4;
    constexpr int CT = OUT / 16;

    for (int tile = blockIdx.x; tile < NT; tile += gridDim.x) {
        int rowBase = tile * 64;

        if constexpr (AMODE == 0) {
            const float* X = (const float*)Xv;
            for (int g = t; g < 64 * (K / 8); g += 256) {
                int r = g / (K / 8), q = g - r * (K / 8);
                int gr = rowBase + r;
                unsigned short us[8];
                if (gr < N) {
                    float4 v0 = *(const float4*)(X + (size_t)gr * ldx + q * 8);
                    float4 v1 = *(const float4*)(X + (size_t)gr * ldx + q * 8 + 4);
                    us[0] = f2b(v0.x); us[1] = f2b(v0.y); us[2] = f2b(v0.z); us[3] = f2b(v0.w);
                    us[4] = f2b(v1.x); us[5] = f2b(v1.y); us[6] = f2b(v1.z); us[7] = f2b(v1.w);
                } else {
#pragma unroll
                    for (int j = 0; j < 8; j++) us[j] = 0;
                }
                *(uint4*)&As[r * LDK + q * 8] = *(uint4*)us;
            }
        } else {   // fp8 A
            const unsigned char* X = (const unsigned char*)Xv;
            for (int g = t; g < 64 * (K / 8); g += 256) {
                int r = g / (K / 8), q = g - r * (K / 8);
                int gr = rowBase + r;
                unsigned short us[8];
                if (gr < N) {
                    uint2 u = *(const uint2*)(X + (size_t)gr * ldx + q * 8);
                    f32x2 v0 = __builtin_amdgcn_cvt_pk_f32_fp8((int)u.x, false);
                    f32x2 v1 = __builtin_amdgcn_cvt_pk_f32_fp8((int)u.x, true);
                    f32x2 v2 = __builtin_amdgcn_cvt_pk_f32_fp8((int)u.y, false);
                    f32x2 v3 = __builtin_amdgcn_cvt_pk_f32_fp8((int)u.y, true);
                    us[0] = f2b(v0[0]); us[1] = f2b(v0[1]); us[2] = f2b(v1[0]); us[3] = f2b(v1[1]);
                    us[4] = f2b(v2[0]); us[5] = f2b(v2[1]); us[6] = f2b(v3[0]); us[7] = f2b(v3[1]);
                } else {
#pragma unroll
                    for (int j = 0; j < 8; j++) us[j] = 0;
                }
                *(uint4*)&As[r * LDK + q * 8] = *(uint4*)us;
            }
        }
        __syncthreads();

        f32x4 acc[CT];
#pragma unroll
        for (int c = 0; c < CT; c++) acc[c] = (f32x4){0.f, 0.f, 0.f, 0.f};

        const unsigned short* arow = &As[(wv * 16 + lm) * LDK + lq * 8];
#pragma unroll
        for (int kt = 0; kt < K / 32; kt++) {
            bf16x8 a = *(const bf16x8*)(arow + kt * 32);
#pragma unroll
            for (int c = 0; c < CT; c++) {
                bf16x8 b = *(const bf16x8*)&Bs[(c * 16 + lm) * LDK + kt * 32 + lq * 8];
                acc[c] = __builtin_amdgcn_mfma_f32_16x16x32_bf16(a, b, acc[c], 0, 0, 0);
            }
        }

        // epilogue: C/D layout col=lane&15, row=(lane>>4)*4+reg [m89/m91]
        int r0 = rowBase + wv * 16 + lq * 4;
        if constexpr (EPI == 0) {
#pragma unroll
            for (int r = 0; r < 4; r++) {
                int gr = r0 + r;
                float scale = (gr < N) ? sb[gr] * (S_FP8 * AIN) : 0.f;
#pragma unroll
                for (int c = 0; c < CT; c++) {
                    int colg = c * 16 + lm;
                    ((unsigned char*)Yv)[(size_t)gr * OUT + colg] = f2fp8(acc[c][r] * scale);
                }
            }
        } else if constexpr (EPI == 1) {
#pragma unroll
            for (int r = 0; r < 4; r++) {
                int gr = r0 + r;
                if (gr < N) {
#pragma unroll
                    for (int c = 0; c < CT; c++) {
                        int colg = c * 16 + lm;
                        float bb = (colg < 128) ? sb[colg] : w3b[colg - 128];
                        float v = fmaxf(acc[c][r] * AIN + bb, 0.f);
                        ((unsigned char*)Yv)[(size_t)gr * OUT + colg] = f2fp8(v * S2);
                    }
                }
            }
        } else if constexpr (EPI == 2) {
            float l[4][8];
#pragma unroll
            for (int r = 0; r < 4; r++)
#pragma unroll
                for (int a = 0; a < 8; a++) l[r][a] = 0.f;
#pragma unroll
            for (int c = 0; c < CT; c++) {
                int colg = c * 16 + lm;
#pragma unroll
                for (int r = 0; r < 4; r++) {
                    float v = fmaxf(acc[c][r] * AIN + sb[colg], 0.f);
#pragma unroll
                    for (int a = 0; a < 8; a++)
                        l[r][a] = fmaf(v, w3b[colg * 8 + a], l[r][a]);
                }
            }
#pragma unroll
            for (int w = 1; w < 16; w <<= 1)
#pragma unroll
                for (int r = 0; r < 4; r++)
#pragma unroll
                    for (int a = 0; a < 8; a++)
                        l[r][a] += __shfl_xor(l[r][a], w, 64);
            if (lm < 8) {
#pragma unroll
                for (int r = 0; r < 4; r++) {
                    int gr = r0 + r;
                    if (gr < N) {
                        float lg[8], m = -1e30f;
#pragma unroll
                        for (int a = 0; a < 8; a++) { lg[a] = l[r][a] + b3[a]; m = fmaxf(m, lg[a]); }
                        float sum = 0.f;
#pragma unroll
                        for (int a = 0; a < 8; a++) { lg[a] = expf(lg[a] - m); sum += lg[a]; }
                        ((float*)Yv)[(size_t)gr * 9 + lm] = lg[lm] / sum;
                    }
                }
            }
        } else {   // EPI == 3
            float lv[4] = {0.f, 0.f, 0.f, 0.f};
#pragma unroll
            for (int c = 0; c < CT; c++) {
                int colg = c * 16 + lm;
#pragma unroll
                for (int r = 0; r < 4; r++) {
                    float v = fmaxf(acc[c][r] * AIN + sb[colg], 0.f);
                    lv[r] = fmaf(v, w3b[colg], lv[r]);
                }
            }
#pragma unroll
            for (int w = 1; w < 16; w <<= 1)
#pragma unroll
                for (int r = 0; r < 4; r++) lv[r] += __shfl_xor(lv[r], w, 64);
            if (lm == 0) {
#pragma unroll
                for (int r = 0; r < 4; r++) {
                    int gr = r0 + r;
                    if (gr < N) ((float*)Yv)[(size_t)gr * 9 + 8] = lv[r] + b3[0];
                }
            }
        }
        __syncthreads();
    }
}

// ---------------- aggregation: fp8 gather, packed-f32 acc, fp8 out ----------------

template <bool RELU>
__global__ __launch_bounds__(256) void agg128_k(
    const unsigned char* __restrict__ H,   // [(Npad+64),128] fp8, rows>=N zero
    const int* __restrict__ rowptr, const int* __restrict__ col,
    const float* __restrict__ dinv, const float* __restrict__ bias,
    unsigned char* __restrict__ Y, int N, int Ecap) {
    int tid = threadIdx.x;
    int node = blockIdx.x * 4 + (tid >> 6);
    if (node >= N) return;
    int lane = tid & 63;
    int grp = lane >> 4;
    int li8 = (lane & 15) * 8;

    f32x2 a01 = {0.f, 0.f}, a23 = {0.f, 0.f}, a45 = {0.f, 0.f}, a67 = {0.f, 0.f};
    if (grp == 0) {
        uint2 u = *(const uint2*)(H + (size_t)node * 128 + li8);
        acc8(u, a01, a23, a45, a67);
    }

    int start = rowptr[node], end = rowptr[node + 1];
    for (int e0 = start; e0 < end; e0 += 64) {
        int cv = col[min(e0 + lane, Ecap - 1)];
        int quads = min(64, end - e0) >> 2;
        for (int q = 0; q < quads; q += 2) {
            int s0 = __shfl(cv, 4 * q + grp, 64);
            int s1 = __shfl(cv, 4 * q + 4 + grp, 64);
            uint2 u0 = *(const uint2*)(H + (size_t)s0 * 128 + li8);
            uint2 u1 = *(const uint2*)(H + (size_t)s1 * 128 + li8);
            acc8(u0, a01, a23, a45, a67);
            acc8(u1, a01, a23, a45, a67);
        }
    }

#pragma unroll
    for (int w = 16; w < 64; w <<= 1) {
        a01[0] += __shfl_xor(a01[0], w, 64); a01[1] += __shfl_xor(a01[1], w, 64);
        a23[0] += __shfl_xor(a23[0], w, 64); a23[1] += __shfl_xor(a23[1], w, 64);
        a45[0] += __shfl_xor(a45[0], w, 64); a45[1] += __shfl_xor(a45[1], w, 64);
        a67[0] += __shfl_xor(a67[0], w, 64); a67[1] += __shfl_xor(a67[1], w, 64);
    }

    if (grp == 0) {
        float dv = dinv[node] * S_FP8_INV;
        float4 b0 = *(const float4*)(bias + li8);
        float4 b1 = *(const float4*)(bias + li8 + 4);
        float o0 = a01[0] * dv + b0.x, o1 = a01[1] * dv + b0.y;
        float o2 = a23[0] * dv + b0.z, o3 = a23[1] * dv + b0.w;
        float o4 = a45[0] * dv + b1.x, o5 = a45[1] * dv + b1.y;
        float o6 = a67[0] * dv + b1.z, o7 = a67[1] * dv + b1.w;
        if (RELU) {
            o0 = fmaxf(o0, 0.f); o1 = fmaxf(o1, 0.f); o2 = fmaxf(o2, 0.f); o3 = fmaxf(o3, 0.f);
            o4 = fmaxf(o4, 0.f); o5 = fmaxf(o5, 0.f); o6 = fmaxf(o6, 0.f); o7 = fmaxf(o7, 0.f);
        }
        unsigned char us[8] = {f2fp8(o0 * S2), f2fp8(o1 * S2), f2fp8(o2 * S2), f2fp8(o3 * S2),
                               f2fp8(o4 * S2), f2fp8(o5 * S2), f2fp8(o6 * S2), f2fp8(o7 * S2)};
        *(uint2*)(Y + (size_t)node * 128 + li8) = *(uint2*)us;
    }
}

__global__ __launch_bounds__(256) void agg64_k(
    const unsigned char* __restrict__ H,   // [(Npad+64),64] fp8, rows>=N zero
    const int* __restrict__ rowptr, const int* __restrict__ col,
    const float* __restrict__ dinv, const float* __restrict__ bias,
    unsigned char* __restrict__ Y, int N, int Ecap) {
    int tid = threadIdx.x;
    int node = blockIdx.x * 4 + (tid >> 6);
    if (node >= N) return;
    int lane = tid & 63;
    int grp = lane >> 3;
    int li8 = (lane & 7) * 8;

    f32x2 a01 = {0.f, 0.f}, a23 = {0.f, 0.f}, a45 = {0.f, 0.f}, a67 = {0.f, 0.f};
    if (grp == 0) {
        uint2 u = *(const uint2*)(H + (size_t)node * 64 + li8);
        acc8(u, a01, a23, a45, a67);
    }

    int start = rowptr[node], end = rowptr[node + 1];
    for (int e0 = start; e0 < end; e0 += 64) {
        int cv = col[min(e0 + lane, Ecap - 1)];
        int octs = min(64, end - e0) >> 3;
        int o = 0;
        for (; o + 2 <= octs; o += 2) {
            int s0 = __shfl(cv, 8 * o + grp, 64);
            int s1 = __shfl(cv, 8 * o + 8 + grp, 64);
            uint2 u0 = *(const uint2*)(H + (size_t)s0 * 64 + li8);
            uint2 u1 = *(const uint2*)(H + (size_t)s1 * 64 + li8);
            acc8(u0, a01, a23, a45, a67);
            acc8(u1, a01, a23, a45, a67);
        }
        if (o < octs) {
            int s0 = __shfl(cv, 8 * o + grp, 64);
            uint2 u0 = *(const uint2*)(H + (size_t)s0 * 64 + li8);
            acc8(u0, a01, a23, a45, a67);
        }
    }

#pragma unroll
    for (int w = 8; w < 64; w <<= 1) {
        a01[0] += __shfl_xor(a01[0], w, 64); a01[1] += __shfl_xor(a01[1], w, 64);
        a23[0] += __shfl_xor(a23[0], w, 64); a23[1] += __shfl_xor(a23[1], w, 64);
        a45[0] += __shfl_xor(a45[0], w, 64); a45[1] += __shfl_xor(a45[1], w, 64);
        a67[0] += __shfl_xor(a67[0], w, 64); a67[1] += __shfl_xor(a67[1], w, 64);
    }

    if (grp == 0) {
        float dv = dinv[node] * S_FP8_INV;
        float4 b0 = *(const float4*)(bias + li8);
        float4 b1 = *(const float4*)(bias + li8 + 4);
        unsigned char us[8] = {
            f2fp8((a01[0] * dv + b0.x) * S2), f2fp8((a01[1] * dv + b0.y) * S2),
            f2fp8((a23[0] * dv + b0.z) * S2), f2fp8((a23[1] * dv + b0.w) * S2),
            f2fp8((a45[0] * dv + b1.x) * S2), f2fp8((a45[1] * dv + b1.y) * S2),
            f2fp8((a67[0] * dv + b1.z) * S2), f2fp8((a67[1] * dv + b1.w) * S2)};
        *(uint2*)(Y + (size_t)node * 64 + li8) = *(uint2*)us;
    }
}

// ---------------- launch ----------------

extern "C" void kernel_launch(void* const* d_in, const int* in_sizes, int n_in,
                              void* d_out, int out_size, void* d_ws, size_t ws_size,
                              hipStream_t stream) {
    const float* x   = (const float*)d_in[0];
    const int*   ei  = (const int*)d_in[1];
    const float* W1  = (const float*)d_in[2];  const float* b1  = (const float*)d_in[3];
    const float* W2  = (const float*)d_in[4];  const float* b2  = (const float*)d_in[5];
    const float* W3  = (const float*)d_in[6];  const float* b3  = (const float*)d_in[7];
    const float* Wa1 = (const float*)d_in[8];  const float* ba1 = (const float*)d_in[9];
    const float* Wa2 = (const float*)d_in[10]; const float* ba2 = (const float*)d_in[11];
    const float* Wa3 = (const float*)d_in[12]; const float* ba3 = (const float*)d_in[13];
    const float* Wc1 = (const float*)d_in[14]; const float* bc1 = (const float*)d_in[15];
    const float* Wc2 = (const float*)d_in[16]; const float* bc2 = (const float*)d_in[17];
    const float* Wc3 = (const float*)d_in[18]; const float* bc3 = (const float*)d_in[19];
    float* out = (float*)d_out;

    const int N = in_sizes[0] / 128;     // 100000
    const int E = in_sizes[1] / 2;       // 3200000
    const int* src = ei;
    const int* dst = ei + E;
    const int Ecap = E + 8 * N;          // padded-CSR capacity
    const int Npad = ((N + 63) / 64) * 64;
    const int NT   = (N + 63) / 64;      // 1563 row tiles

    // workspace layout (all activations fp8)
    size_t off = 0;
    auto take = [&](size_t bytes) { size_t o = off; off = WS_ALIGN(off + bytes); return o; };
    char* ws = (char*)d_ws;
    unsigned char* P1   = (unsigned char*)(ws + take((size_t)(Npad + 64) * 128)); // 12.8MB hprime
    unsigned char* H1   = (unsigned char*)(ws + take((size_t)(Npad + 64) * 128)); // 12.8MB h/h3
    unsigned char* A1C1 = (unsigned char*)(ws + take((size_t)N * 256));           // 25.6MB
    int*           col  = (int*)(ws + take((size_t)Ecap * 4));                    // 16MB
    unsigned short* wt  = (unsigned short*)(ws + take(73728 * 2));
    float* dinv   = (float*)(ws + take((size_t)(N + 64) * 4));
    int*   cnt    = (int*)  (ws + take((size_t)N * 4));
    int*   rowptr = (int*)  (ws + take((size_t)(N + 1) * 4));
    int*   bcnt   = (int*)  (ws + take((size_t)RNG * NB * 4));
    int*   base   = (int*)  (ws + take((size_t)RNG * NB * 4));
    int*   rtot   = (int*)  (ws + take(RNG * 4));
    int*   bstart = (int*)  (ws + take((RNG + 1) * 4));
    int*   bsum   = (int*)  (ws + take(512 * 4));
    int*   boff   = (int*)  (ws + take(512 * 4));
    // aliases inside A1C1 (dead until head L1, after fill2):
    //   bucket 12.8MB at +0, hist 6.4MB at +12.8MB
    unsigned* bucket = (unsigned*)A1C1;
    int* hist = (int*)(A1C1 + (size_t)E * 4);
    (void)ws_size; (void)n_in; (void)out_size;

    const int nb  = (N + 255) / 256;     // 391 (<512)
    const int GG  = 512;                 // gemm2 grid

    prep_w_k<<<288, 256, 0, stream>>>(W1, W2, W3, Wa1, Wc1, Wa2, Wc2, wt);
    const unsigned short* W1t  = wt;
    const unsigned short* W2t  = wt + 16384;
    const unsigned short* W3t  = wt + 32768;
    const unsigned short* Wh1t = wt + 40960;   // [256][64] concat actor|critic L1
    const unsigned short* Wa2t = wt + 57344;
    const unsigned short* Wc2t = wt + 65536;

    // CSR build
    bucket_count_k<<<NB, 256, 0, stream>>>(dst, bcnt, E);
    rsum_k<<<RNG, 256, 0, stream>>>(bcnt, base, rtot);
    rstart_k<<<1, 64, 0, stream>>>(rtot, bstart);
    bucket_scatter_k<<<NB, 256, 0, stream>>>(src, dst, base, bstart, bucket, E);
    hist_bucket_k<<<RNG * CHK, 256, 0, stream>>>(bucket, bstart, hist);
    sum_hist_dinv_chunk_k<<<nb, 256, 0, stream>>>(hist, cnt, dinv, bsum, N);
    scan_mid_k<<<1, 512, 0, stream>>>(bsum, boff, nb, rowptr, N);
    scan_off_pad_k<<<nb, 256, 0, stream>>>(cnt, boff, rowptr, hist, col, N);
    fill2_k<<<RNG * CHK, 256, 0, stream>>>(bucket, bstart, hist, col);

    // GCN layer 1..3 (P1 = hprime fp8 S_FP8; H1 = h/h3 fp8 S2)
    gemm2_k<128, 128, 0, 0><<<GG, 256, 0, stream>>>(
        x, 128, W1t, dinv, nullptr, nullptr, P1, N, NT);
    agg128_k<true><<<(N + 3) / 4, 256, 0, stream>>>(P1, rowptr, col, dinv, b1, H1, N, Ecap);
    gemm2_k<128, 128, 0, 2><<<GG, 256, 0, stream>>>(
        H1, 128, W2t, dinv, nullptr, nullptr, P1, N, NT);
    agg128_k<true><<<(N + 3) / 4, 256, 0, stream>>>(P1, rowptr, col, dinv, b2, H1, N, Ecap);
    gemm2_k<128, 64, 0, 2><<<GG, 256, 0, stream>>>(
        H1, 128, W3t, dinv, nullptr, nullptr, P1, N, NT);
    agg64_k<<<(N + 3) / 4, 256, 0, stream>>>(P1, rowptr, col, dinv, b3, H1, N, Ecap);

    // heads (bucket/hist in A1C1 dead; H1 holds h3 fp8)
    gemm2_k<64, 256, 1, 2><<<GG, 256, 0, stream>>>(
        H1, 64, Wh1t, ba1, bc1, nullptr, A1C1, N, NT);
    gemm2_k<128, 64, 2, 2><<<GG, 256, 0, stream>>>(
        A1C1, 256, Wa2t, ba2, Wa3, ba3, out, N, NT);
    gemm2_k<128, 64, 3, 2><<<GG, 256, 0, stream>>>(
        A1C1 + 128, 256, Wc2t, bc2, Wc3, bc3, out, N, NT);
}